// Round 3
// baseline (127.478 us; speedup 1.0000x reference)
//
#include <hip/hip_runtime.h>

#define NB 128
#define NS 8192
#define NK 16
#define NC 64          // chunks per sequence
#define NL (NS / NC)   // 128 steps per chunk

#define LOG2E 1.4426950408889634f
#define HLOG2PI 0.918938533204672742f
#define LN2 0.69314718055994531f

__device__ __forceinline__ float fexp2(float x) { return __builtin_amdgcn_exp2f(x); }
__device__ __forceinline__ float flog2(float x) { return __builtin_amdgcn_logf(x); }

__device__ __forceinline__ float gsum16(float v) {
    v += __shfl_xor(v, 1, 16);
    v += __shfl_xor(v, 2, 16);
    v += __shfl_xor(v, 4, 16);
    v += __shfl_xor(v, 8, 16);
    return v;
}
__device__ __forceinline__ float gmax16(float v) {
    v = fmaxf(v, __shfl_xor(v, 1, 16));
    v = fmaxf(v, __shfl_xor(v, 2, 16));
    v = fmaxf(v, __shfl_xor(v, 4, 16));
    v = fmaxf(v, __shfl_xor(v, 8, 16));
    return v;
}

// DPP row-rotate by K within 16-lane rows (VALU pipe, no LDS).
template <int K>
__device__ __forceinline__ int rotk(int x) {
    return __builtin_amdgcn_update_dpp(0, x, 0x120 + K, 0xF, 0xF, false);
}

// Phase 1: thread (b, chunk c, column r) evolves basis vector e_r through the
// chunk: W <- diag(lik_t) * A * W,  A = amb*I + bco*11^T.  Lane r computes only
// its own state's likelihood (1 exp); the 16-lane group shares via DPP row
// rotations on the VALU pipe.  W is kept in per-lane ROTATED layout:
// W'[k] = W[sigma_k(r)] where sigma_k is the HW's row_ror:k source map — the
// layout is self-consistent regardless of rotation direction; the true state
// index is recovered at store time via sid[k] = row_ror_k(lane_id).
__global__ __launch_bounds__(256) void hmm_phase1(const float* __restrict__ obvs,
                                                  const float* __restrict__ mu,
                                                  const float* __restrict__ log_sigma,
                                                  float* __restrict__ wsW,
                                                  float* __restrict__ wsM,
                                                  float* __restrict__ wsS,
                                                  float* __restrict__ out) {
    int tid = blockIdx.x * blockDim.x + threadIdx.x;
    if (tid == 0) out[0] = 0.0f;              // replaces memset dispatch
    int r = tid & 15;
    int g = tid >> 4;          // g = b*NC + c
    int b = g >> 6;
    int c = g & (NC - 1);

    // own-state emission coeffs: lik_r(x) = exp2(A2*x^2 + B2*x + C2)
    float ls = log_sigma[r];
    float mk = mu[r];
    float iv = fexp2(-2.0f * LOG2E * ls);     // 1/sigma^2
    float A2 = -0.5f * LOG2E * iv;
    float B2 = LOG2E * mk * iv;
    float C2 = LOG2E * (-0.5f * mk * mk * iv - ls - HLOG2PI);

    float W[16];
#pragma unroll
    for (int k = 0; k < 16; ++k) W[k] = (k == 0) ? 1.0f : 0.0f;  // identity in rotated layout
    int ilog = 0;

    const float amb = 0.9f - 0.1f / 15.0f;
    const float bco = 0.1f / 15.0f;

    const float* ob = obvs + (long)b * NS;
    int t0 = c * NL + (c == 0 ? 1 : 0);       // t=0 handled as init vector in phase3
    int t1 = c * NL + NL;

    float x0 = ob[t0];
    float x1 = ob[(t0 + 1 < t1) ? t0 + 1 : t1 - 1];
    for (int t = t0; t < t1; ++t) {
        float xn = ob[(t + 2 < t1) ? (t + 2) : (t1 - 1)];   // 2-deep prefetch
        float s0 = (W[0] + W[1]) + (W[2] + W[3]);
        float s1 = (W[4] + W[5]) + (W[6] + W[7]);
        float s2 = (W[8] + W[9]) + (W[10] + W[11]);
        float s3 = (W[12] + W[13]) + (W[14] + W[15]);
        float T = (s0 + s1) + (s2 + s3);
        if (T < 0x1p-40f) {                    // T only shrinks; keep it normal
#pragma unroll
            for (int k = 0; k < 16; ++k) W[k] *= 0x1p80f;
            T *= 0x1p80f;
            ilog -= 80;
        }
        float myl = fexp2(fmaf(x0, fmaf(x0, A2, B2), C2));  // ONE exp per lane
        int mi = __float_as_int(myl);
        float bT = bco * T;
        float lk[16];
        lk[0] = myl;
        lk[1]  = __int_as_float(rotk<1>(mi));
        lk[2]  = __int_as_float(rotk<2>(mi));
        lk[3]  = __int_as_float(rotk<3>(mi));
        lk[4]  = __int_as_float(rotk<4>(mi));
        lk[5]  = __int_as_float(rotk<5>(mi));
        lk[6]  = __int_as_float(rotk<6>(mi));
        lk[7]  = __int_as_float(rotk<7>(mi));
        lk[8]  = __int_as_float(rotk<8>(mi));
        lk[9]  = __int_as_float(rotk<9>(mi));
        lk[10] = __int_as_float(rotk<10>(mi));
        lk[11] = __int_as_float(rotk<11>(mi));
        lk[12] = __int_as_float(rotk<12>(mi));
        lk[13] = __int_as_float(rotk<13>(mi));
        lk[14] = __int_as_float(rotk<14>(mi));
        lk[15] = __int_as_float(rotk<15>(mi));
#pragma unroll
        for (int k = 0; k < 16; ++k) W[k] = fmaf(amb, W[k], bT) * lk[k];
        x0 = x1;
        x1 = xn;
    }

    // recover the rotation source map (self-consistent with in-loop rotations)
    int sid[16];
    sid[0] = r;
    sid[1]  = rotk<1>(r);
    sid[2]  = rotk<2>(r);
    sid[3]  = rotk<3>(r);
    sid[4]  = rotk<4>(r);
    sid[5]  = rotk<5>(r);
    sid[6]  = rotk<6>(r);
    sid[7]  = rotk<7>(r);
    sid[8]  = rotk<8>(r);
    sid[9]  = rotk<9>(r);
    sid[10] = rotk<10>(r);
    sid[11] = rotk<11>(r);
    sid[12] = rotk<12>(r);
    sid[13] = rotk<13>(r);
    sid[14] = rotk<14>(r);
    sid[15] = rotk<15>(r);

    // normalize chunk columns to the chunk's max column log-sum
    float s0 = (W[0] + W[1]) + (W[2] + W[3]);
    float s1 = (W[4] + W[5]) + (W[6] + W[7]);
    float s2 = (W[8] + W[9]) + (W[10] + W[11]);
    float s3 = (W[12] + W[13]) + (W[14] + W[15]);
    float Tf = (s0 + s1) + (s2 + s3);
    float lg = (float)ilog + flog2(Tf);
    float mx = gmax16(lg);
    float sc = fexp2((float)ilog - mx);
    float* dst = wsW + (long)g * 256 + r;      // layout [g][j][r]
#pragma unroll
    for (int k = 0; k < 16; ++k) dst[sid[k] * 16] = W[k] * sc;
    wsS[g * 16 + r] = Tf * sc;                 // column sums (max over r == 1)
    if (r == 0) wsM[g] = mx;
}

// Phase 2: one block per (b, half). Stages 32 chunk matrices + colsums into LDS,
// tree-combines 5 levels (later*earlier) with per-level max-colsum rescaling.
__global__ __launch_bounds__(256) void hmm_phase2(const float* __restrict__ wsW,
                                                  const float* __restrict__ wsM,
                                                  const float* __restrict__ wsS,
                                                  float* __restrict__ wsW2,
                                                  float* __restrict__ wsM2) {
    __shared__ float X[32 * 256];   // 32 KB
    __shared__ float Y[16 * 256];   // 16 KB
    __shared__ float csX[32 * 16];
    __shared__ float csY[16 * 16];
    __shared__ float invS[16];
    __shared__ float smM[32];
    __shared__ float logAcc;

    int bi = blockIdx.x;            // 0..255
    int b = bi >> 1;
    int c0 = (bi & 1) * 32;
    int tid = threadIdx.x;

    const float4* src = (const float4*)(wsW + ((long)b * NC + c0) * 256);
    float4* dstX = (float4*)X;
    for (int i = tid; i < 2048; i += 256) dstX[i] = src[i];
    for (int i = tid; i < 512; i += 256) csX[i] = wsS[(b * NC + c0) * 16 + i];
    if (tid < 32) smM[tid] = wsM[b * NC + c0 + tid];
    if (tid == 0) logAcc = 0.0f;
    __syncthreads();

    float* cur = X; float* nxt = Y;
    float* ccs = csX; float* ncs = csY;
    int npairs = 16;
    for (int l = 0; l < 5; ++l) {
        {
            int i0 = tid >> 4, r = tid & 15;
            for (int i = i0; i < npairs; i += 16) {
                const float* Ma = cur + (2 * i) * 256;
                const float* cb = ccs + (2 * i + 1) * 16;
                float s = 0.0f;
#pragma unroll
                for (int k = 0; k < 16; ++k) s = fmaf(cb[k], Ma[k * 16 + r], s);
                float S = gmax16(s);
                float is = 1.0f / S;
                ncs[i * 16 + r] = s * is;
                if (r == 0) { invS[i] = is; atomicAdd(&logAcc, flog2(S)); }
            }
        }
        __syncthreads();
        {
            int j = tid >> 4, r = tid & 15;
            for (int i = 0; i < npairs; ++i) {
                const float* Ma = cur + (2 * i) * 256;
                const float* Mb = cur + (2 * i + 1) * 256 + j * 16;
                float br[16];
                *(float4*)&br[0]  = ((const float4*)Mb)[0];
                *(float4*)&br[4]  = ((const float4*)Mb)[1];
                *(float4*)&br[8]  = ((const float4*)Mb)[2];
                *(float4*)&br[12] = ((const float4*)Mb)[3];
                float acc = br[0] * Ma[r];
#pragma unroll
                for (int k = 1; k < 16; ++k) acc = fmaf(br[k], Ma[k * 16 + r], acc);
                nxt[i * 256 + tid] = acc * invS[i];
            }
        }
        __syncthreads();
        float* t1 = cur; cur = nxt; nxt = t1;
        float* t2 = ccs; ccs = ncs; ncs = t2;
        npairs >>= 1;
    }
    wsW2[(long)bi * 256 + tid] = cur[tid];
    if (tid < 16) {
        float pm = smM[tid] + smM[tid + 16];
        pm = gsum16(pm);
        if (tid == 0) wsM2[bi] = pm + logAcc;
    }
}

// Phase 3: 16 lanes per b — init vector, apply the 2 half-matrices, logsumexp.
__global__ __launch_bounds__(256) void hmm_phase3(const float* __restrict__ obvs,
                                                  const float* __restrict__ mu,
                                                  const float* __restrict__ log_sigma,
                                                  const float* __restrict__ prior_logits,
                                                  const float* __restrict__ wsW2,
                                                  const float* __restrict__ wsM2,
                                                  float* __restrict__ out) {
    int tid = blockIdx.x * blockDim.x + threadIdx.x;
    int j = tid & 15;
    int b = tid >> 4;

    float ls = log_sigma[j];
    float mk = mu[j];
    float iv = fexp2(-2.0f * LOG2E * ls);
    float A2 = -0.5f * LOG2E * iv;
    float B2 = LOG2E * mk * iv;
    float C2 = LOG2E * (-0.5f * mk * mk * iv - ls - HLOG2PI);

    float x = obvs[(long)b * NS];
    float lik0 = fexp2(fmaf(x, fmaf(x, A2, B2), C2));
    float e = fexp2(LOG2E * prior_logits[j]);
    float Z = gsum16(e);
    float p = lik0 * e;
    float Plog = -flog2(Z);

    for (int h = 0; h < 2; ++h) {
        const float* M = wsW2 + (long)(b * 2 + h) * 256 + j * 16;
        float mr[16];
        *(float4*)&mr[0]  = ((const float4*)M)[0];
        *(float4*)&mr[4]  = ((const float4*)M)[1];
        *(float4*)&mr[8]  = ((const float4*)M)[2];
        *(float4*)&mr[12] = ((const float4*)M)[3];
        float q = 0.0f;
#pragma unroll
        for (int rr = 0; rr < 16; ++rr) q = fmaf(mr[rr], __shfl(p, rr, 16), q);
        float Tq = gsum16(q);
        p = q / Tq;
        Plog += flog2(Tq) + wsM2[b * 2 + h];
    }
    if (j == 0) atomicAdd(out, Plog * LN2);
}

extern "C" void kernel_launch(void* const* d_in, const int* in_sizes, int n_in,
                              void* d_out, int out_size, void* d_ws, size_t ws_size,
                              hipStream_t stream) {
    const float* obvs = (const float*)d_in[0];
    const float* mu = (const float*)d_in[1];
    const float* log_sigma = (const float*)d_in[2];
    const float* prior_logits = (const float*)d_in[3];
    float* out = (float*)d_out;

    float* wsW = (float*)d_ws;                         // 128*64*256 floats
    float* wsM = wsW + (size_t)NB * NC * 256;
    float* wsS = wsM + (size_t)NB * NC;
    float* wsW2 = wsS + (size_t)NB * NC * 16;
    float* wsM2 = wsW2 + (size_t)NB * 2 * 256;

    hmm_phase1<<<dim3(NB * NC * 16 / 256), dim3(256), 0, stream>>>(obvs, mu, log_sigma,
                                                                   wsW, wsM, wsS, out);
    hmm_phase2<<<dim3(NB * 2), dim3(256), 0, stream>>>(wsW, wsM, wsS, wsW2, wsM2);
    hmm_phase3<<<dim3(NB * 16 / 256), dim3(256), 0, stream>>>(obvs, mu, log_sigma, prior_logits,
                                                              wsW2, wsM2, out);
}

// Round 4
// 120.582 us; speedup vs baseline: 1.0572x; 1.0572x over previous
//
#include <hip/hip_runtime.h>

#define NB 128
#define NS 8192
#define NK 16
#define NC 64          // chunks per sequence
#define NL (NS / NC)   // 128 steps per chunk

#define LOG2E 1.4426950408889634f
#define HLOG2PI 0.918938533204672742f
#define LN2 0.69314718055994531f

__device__ __forceinline__ float fexp2(float x) { return __builtin_amdgcn_exp2f(x); }
__device__ __forceinline__ float flog2(float x) { return __builtin_amdgcn_logf(x); }

__device__ __forceinline__ float gsum16(float v) {
    v += __shfl_xor(v, 1, 16);
    v += __shfl_xor(v, 2, 16);
    v += __shfl_xor(v, 4, 16);
    v += __shfl_xor(v, 8, 16);
    return v;
}
__device__ __forceinline__ float gmax16(float v) {
    v = fmaxf(v, __shfl_xor(v, 1, 16));
    v = fmaxf(v, __shfl_xor(v, 2, 16));
    v = fmaxf(v, __shfl_xor(v, 4, 16));
    v = fmaxf(v, __shfl_xor(v, 8, 16));
    return v;
}

// DPP row-rotate by K within 16-lane rows. mov_dpp: no old operand -> no
// zero-init v_mov per rotation (update_dpp(0,..) cost 1 extra mov each).
template <int K>
__device__ __forceinline__ int rotk(int x) {
    return __builtin_amdgcn_mov_dpp(x, 0x120 + K, 0xF, 0xF, false);
}

// One HMM step in rotated-W layout: W'[k] = fma(amb,W'[k],bco*T) * row_ror_k(lik).
// Rotate-and-consume (no lk[] array) keeps live registers ~= 16+coeffs.
__device__ __forceinline__ void step_fn(float (&W)[16], int& ilog, float xx,
                                        float A2, float B2, float C2) {
    const float amb = 0.9f - 0.1f / 15.0f;
    const float bco = 0.1f / 15.0f;
    float s0 = (W[0] + W[1]) + (W[2] + W[3]);
    float s1 = (W[4] + W[5]) + (W[6] + W[7]);
    float s2 = (W[8] + W[9]) + (W[10] + W[11]);
    float s3 = (W[12] + W[13]) + (W[14] + W[15]);
    float T = (s0 + s1) + (s2 + s3);
    if (T < 0x1p-40f) {                    // T only shrinks (lik<0.6); keep it normal
#pragma unroll
        for (int k = 0; k < 16; ++k) W[k] *= 0x1p80f;
        T *= 0x1p80f;
        ilog -= 80;
    }
    float myl = fexp2(fmaf(xx, fmaf(xx, A2, B2), C2));   // ONE exp per lane
    int mi = __float_as_int(myl);
    float bT = bco * T;
    W[0]  = fmaf(amb, W[0],  bT) * myl;
    W[1]  = fmaf(amb, W[1],  bT) * __int_as_float(rotk<1>(mi));
    W[2]  = fmaf(amb, W[2],  bT) * __int_as_float(rotk<2>(mi));
    W[3]  = fmaf(amb, W[3],  bT) * __int_as_float(rotk<3>(mi));
    W[4]  = fmaf(amb, W[4],  bT) * __int_as_float(rotk<4>(mi));
    W[5]  = fmaf(amb, W[5],  bT) * __int_as_float(rotk<5>(mi));
    W[6]  = fmaf(amb, W[6],  bT) * __int_as_float(rotk<6>(mi));
    W[7]  = fmaf(amb, W[7],  bT) * __int_as_float(rotk<7>(mi));
    W[8]  = fmaf(amb, W[8],  bT) * __int_as_float(rotk<8>(mi));
    W[9]  = fmaf(amb, W[9],  bT) * __int_as_float(rotk<9>(mi));
    W[10] = fmaf(amb, W[10], bT) * __int_as_float(rotk<10>(mi));
    W[11] = fmaf(amb, W[11], bT) * __int_as_float(rotk<11>(mi));
    W[12] = fmaf(amb, W[12], bT) * __int_as_float(rotk<12>(mi));
    W[13] = fmaf(amb, W[13], bT) * __int_as_float(rotk<13>(mi));
    W[14] = fmaf(amb, W[14], bT) * __int_as_float(rotk<14>(mi));
    W[15] = fmaf(amb, W[15], bT) * __int_as_float(rotk<15>(mi));
}

// Phase 1: thread (b, chunk c, column r) evolves basis e_r through its chunk.
// __launch_bounds__(256,4): VGPR cap 128 so W[16] stays in ARCH VGPRs — round-3
// counters (VGPR_Count=28, 173 insts/step) showed the compiler was shuttling the
// arrays through AGPRs with v_accvgpr_read/write every step.
__global__ __launch_bounds__(256, 4) void hmm_phase1(const float* __restrict__ obvs,
                                                     const float* __restrict__ mu,
                                                     const float* __restrict__ log_sigma,
                                                     float* __restrict__ wsW,
                                                     float* __restrict__ wsM,
                                                     float* __restrict__ out) {
    int tid = blockIdx.x * blockDim.x + threadIdx.x;
    if (tid == 0) out[0] = 0.0f;              // replaces memset dispatch
    int r = tid & 15;
    int g = tid >> 4;          // g = b*NC + c
    int b = g >> 6;
    int c = g & (NC - 1);

    float ls = log_sigma[r];
    float mk = mu[r];
    float iv = fexp2(-2.0f * LOG2E * ls);     // 1/sigma^2
    float A2 = -0.5f * LOG2E * iv;
    float B2 = LOG2E * mk * iv;
    float C2 = LOG2E * (-0.5f * mk * mk * iv - ls - HLOG2PI);

    float W[16];
#pragma unroll
    for (int k = 0; k < 16; ++k) W[k] = (k == 0) ? 1.0f : 0.0f;  // identity, rotated layout
    int ilog = 0;

    // float4 obs stream: 1 vmem per 4 steps, one-ahead prefetch
    const float4* ob4 = (const float4*)(obvs + (long)b * NS) + c * (NL / 4);
    float4 xv = ob4[0];
    for (int m = 0; m < NL / 4; ++m) {
        float4 xnext = ob4[(m + 1) & (NL / 4 - 1)];
        if (m | c) step_fn(W, ilog, xv.x, A2, B2, C2);  // skip t=0 (handled in phase23)
        step_fn(W, ilog, xv.y, A2, B2, C2);
        step_fn(W, ilog, xv.z, A2, B2, C2);
        step_fn(W, ilog, xv.w, A2, B2, C2);
        xv = xnext;
    }

    // recover rotation source map (self-consistent with in-loop rotations)
    int sid[16];
    sid[0] = r;
    sid[1]  = rotk<1>(r);
    sid[2]  = rotk<2>(r);
    sid[3]  = rotk<3>(r);
    sid[4]  = rotk<4>(r);
    sid[5]  = rotk<5>(r);
    sid[6]  = rotk<6>(r);
    sid[7]  = rotk<7>(r);
    sid[8]  = rotk<8>(r);
    sid[9]  = rotk<9>(r);
    sid[10] = rotk<10>(r);
    sid[11] = rotk<11>(r);
    sid[12] = rotk<12>(r);
    sid[13] = rotk<13>(r);
    sid[14] = rotk<14>(r);
    sid[15] = rotk<15>(r);

    // normalize chunk columns to the chunk's max column log-sum (max colsum -> 1)
    float s0 = (W[0] + W[1]) + (W[2] + W[3]);
    float s1 = (W[4] + W[5]) + (W[6] + W[7]);
    float s2 = (W[8] + W[9]) + (W[10] + W[11]);
    float s3 = (W[12] + W[13]) + (W[14] + W[15]);
    float Tf = (s0 + s1) + (s2 + s3);
    float lg = (float)ilog + flog2(Tf);
    float mx = gmax16(lg);
    float sc = fexp2((float)ilog - mx);
    float* dst = wsW + (long)g * 256 + r;      // layout [g][j][r], r contiguous
#pragma unroll
    for (int k = 0; k < 16; ++k) dst[sid[k] * 16] = W[k] * sc;
    if (r == 0) wsM[g] = mx;
}

// Phase 2+3 fused: one block per b. Stage 16 chunk mats at a time, combine to
// quad-products, then tree 16->1. NO per-level rescale: chunk matrices are
// column-normalized (max colsum 1) and any product's colsums stay within
// ~135x of each other (elementwise bound from A = amb*I + bco*11^T), so 6
// levels keep colsums in [2^-50, 1] — safely inside fp32. Ends with the init
// vector apply + logsumexp + atomicAdd (was phase3).
__global__ __launch_bounds__(256) void hmm_phase23(const float* __restrict__ obvs,
                                                   const float* __restrict__ mu,
                                                   const float* __restrict__ log_sigma,
                                                   const float* __restrict__ prior_logits,
                                                   const float* __restrict__ wsW,
                                                   const float* __restrict__ wsM,
                                                   float* __restrict__ out) {
    __shared__ float Abuf[16 * 256];   // 16 KB: quad-products, then even tree levels
    __shared__ float Sbuf[24 * 256];   // 24 KB: staging(16) + pair-products(8)
    int b = blockIdx.x;
    int tid = threadIdx.x;
    int j = tid >> 4, r = tid & 15;

    for (int rd = 0; rd < 4; ++rd) {
        const float4* src = (const float4*)(wsW + ((long)b * NC + rd * 16) * 256);
        __syncthreads();                           // Sbuf reuse vs previous round reads
        for (int i = tid; i < 1024; i += 256) ((float4*)Sbuf)[i] = src[i];
        __syncthreads();
        // combine1: 8 pairs (later * earlier) -> Sbuf[16..23]
        for (int i = 0; i < 8; ++i) {
            const float* Ma = Sbuf + (2 * i) * 256;
            const float* Mb = Sbuf + (2 * i + 1) * 256 + j * 16;
            float br[16];
            *(float4*)&br[0]  = ((const float4*)Mb)[0];
            *(float4*)&br[4]  = ((const float4*)Mb)[1];
            *(float4*)&br[8]  = ((const float4*)Mb)[2];
            *(float4*)&br[12] = ((const float4*)Mb)[3];
            float acc = br[0] * Ma[r];
#pragma unroll
            for (int k = 1; k < 16; ++k) acc = fmaf(br[k], Ma[k * 16 + r], acc);
            Sbuf[(16 + i) * 256 + tid] = acc;
        }
        __syncthreads();
        // combine2: 4 pairs -> Abuf[rd*4 + i]
        for (int i = 0; i < 4; ++i) {
            const float* Ma = Sbuf + (16 + 2 * i) * 256;
            const float* Mb = Sbuf + (16 + 2 * i + 1) * 256 + j * 16;
            float br[16];
            *(float4*)&br[0]  = ((const float4*)Mb)[0];
            *(float4*)&br[4]  = ((const float4*)Mb)[1];
            *(float4*)&br[8]  = ((const float4*)Mb)[2];
            *(float4*)&br[12] = ((const float4*)Mb)[3];
            float acc = br[0] * Ma[r];
#pragma unroll
            for (int k = 1; k < 16; ++k) acc = fmaf(br[k], Ma[k * 16 + r], acc);
            Abuf[(rd * 4 + i) * 256 + tid] = acc;
        }
    }
    __syncthreads();

    // tree: 16 -> 8 -> 4 -> 2 -> 1, ping-pong Abuf <-> Sbuf (final lands in Abuf)
    float* cur = Abuf;
    float* nxt = Sbuf;
    for (int n = 8; n >= 1; n >>= 1) {
        for (int i = 0; i < n; ++i) {
            const float* Ma = cur + (2 * i) * 256;
            const float* Mb = cur + (2 * i + 1) * 256 + j * 16;
            float br[16];
            *(float4*)&br[0]  = ((const float4*)Mb)[0];
            *(float4*)&br[4]  = ((const float4*)Mb)[1];
            *(float4*)&br[8]  = ((const float4*)Mb)[2];
            *(float4*)&br[12] = ((const float4*)Mb)[3];
            float acc = br[0] * Ma[r];
#pragma unroll
            for (int k = 1; k < 16; ++k) acc = fmaf(br[k], Ma[k * 16 + r], acc);
            nxt[i * 256 + tid] = acc;
        }
        __syncthreads();
        float* t = cur; cur = nxt; nxt = t;
    }

    // fused phase 3: lanes 0..15 of wave 0
    if (tid < 16) {
        int jj = tid;
        float ls = log_sigma[jj];
        float mk = mu[jj];
        float iv = fexp2(-2.0f * LOG2E * ls);
        float A2 = -0.5f * LOG2E * iv;
        float B2 = LOG2E * mk * iv;
        float C2 = LOG2E * (-0.5f * mk * mk * iv - ls - HLOG2PI);
        float x = obvs[(long)b * NS];                       // t = 0
        float e = fexp2(LOG2E * prior_logits[jj]);
        float Z = gsum16(e);
        float p0 = fexp2(fmaf(x, fmaf(x, A2, B2), C2)) * e;
        // q[jj] = sum_r M[jj][r] * p0[r]
        const float* Mrow = cur + jj * 16;
        float mr[16];
        *(float4*)&mr[0]  = ((const float4*)Mrow)[0];
        *(float4*)&mr[4]  = ((const float4*)Mrow)[1];
        *(float4*)&mr[8]  = ((const float4*)Mrow)[2];
        *(float4*)&mr[12] = ((const float4*)Mrow)[3];
        float q = 0.0f;
#pragma unroll
        for (int rr = 0; rr < 16; ++rr) q = fmaf(mr[rr], __shfl(p0, rr, 16), q);
        float Tq = gsum16(q);
        // accumulated chunk scales
        const float* pm = wsM + b * NC + jj * 4;
        float msum = gsum16(pm[0] + pm[1] + pm[2] + pm[3]);
        if (jj == 0) {
            float res = (flog2(Tq) - flog2(Z) + msum) * LN2;
            atomicAdd(out, res);
        }
    }
}

extern "C" void kernel_launch(void* const* d_in, const int* in_sizes, int n_in,
                              void* d_out, int out_size, void* d_ws, size_t ws_size,
                              hipStream_t stream) {
    const float* obvs = (const float*)d_in[0];
    const float* mu = (const float*)d_in[1];
    const float* log_sigma = (const float*)d_in[2];
    const float* prior_logits = (const float*)d_in[3];
    float* out = (float*)d_out;

    float* wsW = (float*)d_ws;                         // 128*64*256 floats = 8.39 MB
    float* wsM = wsW + (size_t)NB * NC * 256;          // 8192 floats

    hmm_phase1<<<dim3(NB * NC * 16 / 256), dim3(256), 0, stream>>>(obvs, mu, log_sigma,
                                                                   wsW, wsM, out);
    hmm_phase23<<<dim3(NB), dim3(256), 0, stream>>>(obvs, mu, log_sigma, prior_logits,
                                                    wsW, wsM, out);
}